// Round 9
// baseline (39.243 us; speedup 1.0000x reference)
//
#include <hip/hip_runtime.h>
#include <hip/hip_bf16.h>

#define NB 8
#define NS 256
#define NN 128
#define NC 64
#define NH 4
#define AH 128
#define HID 256
#define FH 32
#define SPB 4   // s-values per block

typedef float f32x4 __attribute__((ext_vector_type(4)));

// One fused kernel. 512 blocks = 8 b x 64 s-groups, 256 threads.
// Phase 1: per-block redundant ffn-fold (thread t folds row o=t) -> LDS.
// Phase 2: FIRE bias (t<128) -> LDS.
// Phase 3: joint scan T + Bs[0..3] (4 threads/cluster) -> P -> LDS.
// Phase 4: stores, 4 s-values x 16 linear rows per wave.
__global__ __launch_bounds__(256) void fused_kernel(
    const int* __restrict__ src,      // (B,S,N) int32 {0,1}
    const int* __restrict__ labels,   // (B,N)
    const float* __restrict__ sp_d, const float* __restrict__ tp_d,
    const float* __restrict__ c_sp_p, const float* __restrict__ sp_w1, const float* __restrict__ sp_w2,
    const float* __restrict__ c_tp_p, const float* __restrict__ tp_w1, const float* __restrict__ tp_w2,
    const float* __restrict__ attn_w,
    const float* __restrict__ val_w, const float* __restrict__ val_b,
    const float* __restrict__ ffn_w, const float* __restrict__ ffn_b,
    float* __restrict__ out)          // (B,S,C,HID) float32
{
    __shared__ float sC0[HID];
    __shared__ float sW[HID][NH];
    __shared__ float sE[NN];
    __shared__ float sEx[SPB][NN];
    __shared__ int   sLab[NN];
    __shared__ float sP[SPB][NC][NH];
    __shared__ float sHm[NC];

    const int blk = blockIdx.x;          // b*64 + s_group
    const int b  = blk >> 6;
    const int s0 = (blk & 63) * SPB;
    const int t  = threadIdx.x;

    // ---- Phase 1: fold row o = t ----
    {
        const int o = t;
        const float4* fr = reinterpret_cast<const float4*>(ffn_w + (size_t)o * AH);
        float c0 = ffn_b[o];
        float w[NH] = {0.f, 0.f, 0.f, 0.f};
        #pragma unroll 8
        for (int k4 = 0; k4 < AH / 4; ++k4) {
            const float4 f = fr[k4];
            const int k = k4 * 4;
            const int h = k >> 5;
            c0  = fmaf(f.x, val_b[k], fmaf(f.y, val_b[k+1], fmaf(f.z, val_b[k+2], fmaf(f.w, val_b[k+3], c0))));
            w[h] = fmaf(f.x, val_w[k], fmaf(f.y, val_w[k+1], fmaf(f.z, val_w[k+2], fmaf(f.w, val_w[k+3], w[h]))));
        }
        sC0[o] = c0;
        #pragma unroll
        for (int h = 0; h < NH; ++h) sW[o][h] = w[h];
    }

    // ---- Phase 2: FIRE bias + stage (t < 128) ----
    if (t < NN) {
        const float csp = fmaxf(c_sp_p[0], 0.0f);
        const float ctp = fmaxf(c_tp_p[0], 0.0f);
        const float dsp = sp_d[b * NN + t];
        const float dtp = tp_d[b * NN + t];
        const int   lab = labels[b * NN + t];
        int x[SPB];
        #pragma unroll
        for (int ss = 0; ss < SPB; ++ss)
            x[ss] = src[((size_t)(b * NS + s0 + ss)) * NN + t];
        const float dns = __logf(fmaf(csp, dsp, 1.0f)) / __logf(fmaf(csp, 180.0f, 1.0f));
        const float dnt = __logf(fmaf(ctp, dtp, 1.0f)) / __logf(fmaf(ctp, 365.0f, 1.0f));
        float bias_sp = 0.f, bias_tp = 0.f;
        #pragma unroll
        for (int j = 0; j < FH; ++j) {
            const float zs = dns * sp_w1[j];   // uniform addr -> scalar load
            bias_sp += (zs / (1.0f + __expf(-zs))) * sp_w2[j];
            const float zt = dnt * tp_w1[j];
            bias_tp += (zt / (1.0f + __expf(-zt))) * tp_w2[j];
        }
        const float e = __expf(bias_sp + bias_tp);
        sE[t]   = e;
        sLab[t] = lab;
        #pragma unroll
        for (int ss = 0; ss < SPB; ++ss)
            sEx[ss][t] = x[ss] ? e : 0.f;
    }
    __syncthreads();

    // ---- Phase 3: T + Bs[0..3] joint scan (4 threads/cluster, n = 4i|q) ----
    {
        const int c = t >> 2, q = t & 3;
        float tS = 0.f, bs[SPB] = {0.f, 0.f, 0.f, 0.f};
        #pragma unroll
        for (int i = 0; i < 32; ++i) {
            const int n = (i << 2) | q;
            const bool m = (sLab[n] == c);
            tS += m ? sE[n] : 0.f;
            #pragma unroll
            for (int ss = 0; ss < SPB; ++ss)
                bs[ss] += m ? sEx[ss][n] : 0.f;
        }
        tS += __shfl_xor(tS, 1); tS += __shfl_xor(tS, 2);
        #pragma unroll
        for (int ss = 0; ss < SPB; ++ss) {
            bs[ss] += __shfl_xor(bs[ss], 1);
            bs[ss] += __shfl_xor(bs[ss], 2);
        }
        const bool nz = (tS > 0.f);
        const float ew = __expf(attn_w[q]);    // head h == q
        #pragma unroll
        for (int ss = 0; ss < SPB; ++ss) {
            float p = 0.f;
            if (nz) p = (bs[ss] * ew) / ((tS - bs[ss]) + bs[ss] * ew);
            sP[ss][c][q] = p;
        }
        if (q == 0) sHm[c] = nz ? 1.f : 0.f;
    }
    __syncthreads();

    // ---- Phase 4: stores. Wave w owns rows 16w..16w+15 (linear 16 KB/ss). ----
    const int o0 = (t & 63) * 4;
    const int crow = t >> 6;
    f32x4 c0v, wrow[4];
    #pragma unroll
    for (int i = 0; i < 4; ++i) {
        c0v[i] = sC0[o0 + i];
        wrow[i][0] = sW[o0 + i][0]; wrow[i][1] = sW[o0 + i][1];
        wrow[i][2] = sW[o0 + i][2]; wrow[i][3] = sW[o0 + i][3];
    }
    float* orow0 = out + ((size_t)(b * NS + s0)) * (NC * HID);
    #pragma unroll
    for (int ss = 0; ss < SPB; ++ss) {
        float* orow = orow0 + (size_t)ss * (NC * HID);
        #pragma unroll
        for (int ci = 0; ci < 16; ++ci) {
            const int c = crow * 16 + ci;
            const float p0 = sP[ss][c][0], p1 = sP[ss][c][1];
            const float p2 = sP[ss][c][2], p3 = sP[ss][c][3];
            const float hm = sHm[c];
            f32x4 val;
            #pragma unroll
            for (int i = 0; i < 4; ++i) {
                float v = c0v[i];
                v = fmaf(p0, wrow[i][0], v);
                v = fmaf(p1, wrow[i][1], v);
                v = fmaf(p2, wrow[i][2], v);
                val[i] = fmaf(p3, wrow[i][3], v) * hm;
            }
            *reinterpret_cast<f32x4*>(orow + (size_t)c * HID + o0) = val;
        }
    }
}

extern "C" void kernel_launch(void* const* d_in, const int* in_sizes, int n_in,
                              void* d_out, int out_size, void* d_ws, size_t ws_size,
                              hipStream_t stream) {
    const int*   src    = (const int*)d_in[0];
    const int*   labels = (const int*)d_in[1];
    const float* sp_d   = (const float*)d_in[2];
    const float* tp_d   = (const float*)d_in[3];
    // d_in[4] = num_clusters (fixed 64)
    const float* c_sp   = (const float*)d_in[5];
    const float* sp_w1  = (const float*)d_in[6];
    const float* sp_w2  = (const float*)d_in[7];
    const float* c_tp   = (const float*)d_in[8];
    const float* tp_w1  = (const float*)d_in[9];
    const float* tp_w2  = (const float*)d_in[10];
    const float* attn_w = (const float*)d_in[11];
    // d_in[12] = attn_b: cancels in softmax over n — unused
    const float* val_w  = (const float*)d_in[13];
    const float* val_b  = (const float*)d_in[14];
    const float* ffn_w  = (const float*)d_in[15];
    const float* ffn_b  = (const float*)d_in[16];
    float* out = (float*)d_out;

    fused_kernel<<<NB * NS / SPB, 256, 0, stream>>>(src, labels, sp_d, tp_d,
                                                    c_sp, sp_w1, sp_w2,
                                                    c_tp, tp_w1, tp_w2,
                                                    attn_w, val_w, val_b,
                                                    ffn_w, ffn_b, out);
}

// Round 10
// 36.779 us; speedup vs baseline: 1.0670x; 1.0670x over previous
//
#include <hip/hip_runtime.h>
#include <hip/hip_bf16.h>

#define NB 8
#define NS 256
#define NN 128
#define NC 64
#define NH 4
#define AH 128
#define HID 256
#define FH 32
#define SPB 4   // s-values per out-block

typedef float f32x4 __attribute__((ext_vector_type(4)));

// ws float layout:
// [1536, 1792)   const0[o] = ffn_b[o] + sum_k ffn_w[o][k]*val_b[k]
// [1792, 2816)   W[o][h]  = sum_d ffn_w[o][h*32+d]*val_w[h*32+d]

// 32 blocks x 256 threads; block owns 8 contiguous rows of ffn_w (4 KB).
// Wave-level loads are fully contiguous 1 KB.
__global__ __launch_bounds__(256) void fold_kernel(
    const float* __restrict__ val_w, const float* __restrict__ val_b,
    const float* __restrict__ ffn_w, const float* __restrict__ ffn_b,
    float* __restrict__ ws)
{
    const int t = threadIdx.x;
    const int j = t & 31;
    const int row = blockIdx.x * 8 + (t >> 5);
    const int k = j * 4;

    const f32x4 f  = *reinterpret_cast<const f32x4*>(ffn_w + (size_t)row * AH + k);
    const f32x4 vb = *reinterpret_cast<const f32x4*>(val_b + k);
    const f32x4 vw = *reinterpret_cast<const f32x4*>(val_w + k);

    float c0p = fmaf(f[0], vb[0], fmaf(f[1], vb[1], fmaf(f[2], vb[2], f[3] * vb[3])));
    float whp = fmaf(f[0], vw[0], fmaf(f[1], vw[1], fmaf(f[2], vw[2], f[3] * vw[3])));

    #pragma unroll
    for (int m = 1; m <= 16; m <<= 1) c0p += __shfl_xor(c0p, m);
    #pragma unroll
    for (int m = 1; m <= 4; m <<= 1) whp += __shfl_xor(whp, m);

    if (j == 0) ws[1536 + row] = c0p + ffn_b[row];
    if ((j & 7) == 0) ws[1792 + row * NH + (j >> 3)] = whp;
}

__global__ __launch_bounds__(256) void out_kernel(
    const int* __restrict__ src,      // (B,S,N) int32 {0,1}
    const int* __restrict__ labels,   // (B,N)
    const float* __restrict__ sp_d, const float* __restrict__ tp_d,
    const float* __restrict__ c_sp_p, const float* __restrict__ sp_w1, const float* __restrict__ sp_w2,
    const float* __restrict__ c_tp_p, const float* __restrict__ tp_w1, const float* __restrict__ tp_w2,
    const float* __restrict__ attn_w,
    const float* __restrict__ ws,
    float* __restrict__ out)          // (B,S,C,HID) float32
{
    __shared__ float sE[NN];
    __shared__ f32x4 sEx4[NN];        // {e|x0, e|x1, e|x2, e|x3}
    __shared__ int   sLab[NN];
    __shared__ float sP[SPB][NC][NH];
    __shared__ float sHm[NC];

    const int blk = blockIdx.x;      // b*64 + s_group
    const int b  = blk >> 6;
    const int s0 = (blk & 63) * SPB;
    const int t  = threadIdx.x;

    // Early fetch of per-o constants (independent of barriers below).
    const int o0 = (t & 63) * 4;     // 0..255 step 4
    const int crow = t >> 6;         // 0..3
    const f32x4 c0v = *reinterpret_cast<const f32x4*>(ws + 1536 + o0);
    f32x4 wrow[4];
    #pragma unroll
    for (int i = 0; i < 4; ++i)
        wrow[i] = *reinterpret_cast<const f32x4*>(ws + 1792 + (size_t)(o0 + i) * NH);

    // ---- FIRE bias + stage (t < 128) ----
    if (t < NN) {
        const float csp = fmaxf(c_sp_p[0], 0.0f);
        const float ctp = fmaxf(c_tp_p[0], 0.0f);
        const float dsp = sp_d[b * NN + t];
        const float dtp = tp_d[b * NN + t];
        const int   lab = labels[b * NN + t];
        int x[SPB];
        #pragma unroll
        for (int ss = 0; ss < SPB; ++ss)
            x[ss] = src[((size_t)(b * NS + s0 + ss)) * NN + t];
        const float dns = __logf(fmaf(csp, dsp, 1.0f)) / __logf(fmaf(csp, 180.0f, 1.0f));
        const float dnt = __logf(fmaf(ctp, dtp, 1.0f)) / __logf(fmaf(ctp, 365.0f, 1.0f));
        float bias_sp = 0.f, bias_tp = 0.f;
        #pragma unroll
        for (int j = 0; j < FH; ++j) {
            const float zs = dns * sp_w1[j];   // uniform addr -> scalar load
            bias_sp += (zs / (1.0f + __expf(-zs))) * sp_w2[j];
            const float zt = dnt * tp_w1[j];
            bias_tp += (zt / (1.0f + __expf(-zt))) * tp_w2[j];
        }
        const float e = __expf(bias_sp + bias_tp);
        sE[t]   = e;
        sLab[t] = lab;
        f32x4 ex;
        #pragma unroll
        for (int ss = 0; ss < SPB; ++ss) ex[ss] = x[ss] ? e : 0.f;
        sEx4[t] = ex;
    }
    __syncthreads();

    // ---- T + Bs[0..3] joint scan (4 threads/cluster, n = 4i|q broadcast) ----
    {
        const int c = t >> 2, q = t & 3;
        float tS = 0.f;
        f32x4 bs = {0.f, 0.f, 0.f, 0.f};
        #pragma unroll
        for (int i = 0; i < 32; ++i) {
            const int n = (i << 2) | q;
            if (sLab[n] == c) { tS += sE[n]; bs += sEx4[n]; }
        }
        tS += __shfl_xor(tS, 1); tS += __shfl_xor(tS, 2);
        #pragma unroll
        for (int ss = 0; ss < SPB; ++ss) {
            bs[ss] += __shfl_xor(bs[ss], 1);
            bs[ss] += __shfl_xor(bs[ss], 2);
        }
        const bool nz = (tS > 0.f);
        const float ew = __expf(attn_w[q]);    // head h == q
        #pragma unroll
        for (int ss = 0; ss < SPB; ++ss) {
            float p = 0.f;
            if (nz) p = (bs[ss] * ew) / ((tS - bs[ss]) + bs[ss] * ew);
            sP[ss][c][q] = p;
        }
        if (q == 0) sHm[c] = nz ? 1.f : 0.f;
    }
    __syncthreads();

    // ---- stores: 4 s-values; wave w owns rows 16w..16w+15 (linear 16 KB/ss) ----
    float* orow0 = out + ((size_t)(b * NS + s0)) * (NC * HID);
    #pragma unroll
    for (int ss = 0; ss < SPB; ++ss) {
        float* orow = orow0 + (size_t)ss * (NC * HID);
        #pragma unroll
        for (int ci = 0; ci < 16; ++ci) {
            const int c = crow * 16 + ci;
            const float p0 = sP[ss][c][0], p1 = sP[ss][c][1];
            const float p2 = sP[ss][c][2], p3 = sP[ss][c][3];
            const float hm = sHm[c];
            f32x4 val;
            #pragma unroll
            for (int i = 0; i < 4; ++i) {
                float v = c0v[i];
                v = fmaf(p0, wrow[i][0], v);
                v = fmaf(p1, wrow[i][1], v);
                v = fmaf(p2, wrow[i][2], v);
                val[i] = fmaf(p3, wrow[i][3], v) * hm;
            }
            *reinterpret_cast<f32x4*>(orow + (size_t)c * HID + o0) = val;
        }
    }
}

extern "C" void kernel_launch(void* const* d_in, const int* in_sizes, int n_in,
                              void* d_out, int out_size, void* d_ws, size_t ws_size,
                              hipStream_t stream) {
    const int*   src    = (const int*)d_in[0];
    const int*   labels = (const int*)d_in[1];
    const float* sp_d   = (const float*)d_in[2];
    const float* tp_d   = (const float*)d_in[3];
    // d_in[4] = num_clusters (fixed 64)
    const float* c_sp   = (const float*)d_in[5];
    const float* sp_w1  = (const float*)d_in[6];
    const float* sp_w2  = (const float*)d_in[7];
    const float* c_tp   = (const float*)d_in[8];
    const float* tp_w1  = (const float*)d_in[9];
    const float* tp_w2  = (const float*)d_in[10];
    const float* attn_w = (const float*)d_in[11];
    // d_in[12] = attn_b: cancels in softmax over n — unused
    const float* val_w  = (const float*)d_in[13];
    const float* val_b  = (const float*)d_in[14];
    const float* ffn_w  = (const float*)d_in[15];
    const float* ffn_b  = (const float*)d_in[16];
    float* ws = (float*)d_ws;
    float* out = (float*)d_out;

    fold_kernel<<<32, 256, 0, stream>>>(val_w, val_b, ffn_w, ffn_b, ws);
    out_kernel<<<NB * NS / SPB, 256, 0, stream>>>(src, labels, sp_d, tp_d,
                                                  c_sp, sp_w1, sp_w2,
                                                  c_tp, tp_w1, tp_w2,
                                                  attn_w, ws, out);
}